// Round 3
// baseline (200.529 us; speedup 1.0000x reference)
//
#include <hip/hip_runtime.h>

// QueryAndGroup: ball query (first 32 idx within radius, index order, padded
// with first hit) + grouped_xyz (xyz[idx]-center) + grouped feature gather.
// Shapes: xyz (8,16384,3) f32, new_xyz (8,1024,3) f32, features (8,64,16384) f32
// Out: (8, 3+64, 1024, 32) f32.
//
// R8: FUSED single kernel. 512 blocks (= b*64+c), 512 threads, 2 blocks/CU
// (LDS 65.5KB, VGPR<=128 via launch_bounds(512,4)) -> all blocks co-resident.
// Per block: issue feats[b,c,:] row loads into VGPRs EARLY, compute 16 of
// batch b's ball queries (2 per wave) while loads fly, release-publish idx,
// ds_write the row, spin on done[b]==64 (acquire), then gather.
//  - removes one launch + overlaps feats read with query compute + overlaps
//    gather(b_early) with query(b_late).
//  - deadlock-proof: bounded spin, then self-compute all of batch b's
//    queries (idempotent writes) and proceed.
// R7 post-mortem: NT stores / global_load_lds / full idx reg-prefetch cost
// ~6us net -> reverted to R5-proven bodies; kept mbcnt prefix-count only.

#define BB 8
#define NN 16384
#define SS 1024
#define CC 64
#define NSAMP 32
#define OUTCH (3 + CC)
#define GPB 64            // query groups (blocks) per batch
#define QPG 16            // queries per group

// float(0.04) to match numpy's weak-scalar promotion (NOT 0.2f*0.2f).
#define R2 0.04f

// one ball query, one wave. swave = per-wave LDS scratch (32 ints).
__device__ __forceinline__ void ball_query_one(
    const float* __restrict__ xb,      // xyz + b*NN*3
    const float qx, const float qy, const float qz,
    const int b, const int s, const int lane,
    int* __restrict__ swave,
    int* __restrict__ idxq,
    float* __restrict__ out)
{
    int count = 0;
    for (int base = 0; base < NN; base += 512) {
        float d2[8];
        #pragma unroll
        for (int j = 0; j < 8; ++j) {
            const int i = base + j * 64 + lane;
            const float dx = qx - xb[i * 3 + 0];
            const float dy = qy - xb[i * 3 + 1];
            const float dz = qz - xb[i * 3 + 2];
            // numpy order, no FMA contraction
            d2[j] = __fadd_rn(__fadd_rn(__fmul_rn(dx, dx),
                                        __fmul_rn(dy, dy)),
                              __fmul_rn(dz, dz));
        }
        #pragma unroll
        for (int j = 0; j < 8; ++j) {
            const bool within = d2[j] < R2;
            const unsigned long long m = __ballot(within);
            if (within) {
                // prefix popcount below lane: v_mbcnt_lo/hi (2 VALU)
                const int pre = (int)__builtin_amdgcn_mbcnt_hi(
                    (unsigned)(m >> 32),
                    __builtin_amdgcn_mbcnt_lo((unsigned)m, 0u));
                const int pos = count + pre;
                if (pos < NSAMP) swave[pos] = base + j * 64 + lane;
            }
            count += __popcll(m);   // uniform -> s_bcnt1
        }
        if (count >= NSAMP) break;   // wave-uniform
    }
    // swave is wave-private: DS completion suffices, no block barrier.
    asm volatile("s_waitcnt lgkmcnt(0)" ::: "memory");
    const int cnt = count < NSAMP ? count : NSAMP;
    const int first = (cnt > 0) ? swave[0] : 0;
    if (lane < NSAMP && lane >= cnt) swave[lane] = first;
    asm volatile("s_waitcnt lgkmcnt(0)" ::: "memory");

    if (lane < NSAMP) {
        const int k = lane;
        const int idx = swave[k];
        idxq[((size_t)b * SS + s) * NSAMP + k] = idx;
        // grouped_xyz -> out channels 0..2 (128B coalesced per channel)
        const float gx = xb[idx * 3 + 0] - qx;
        const float gy = xb[idx * 3 + 1] - qy;
        const float gz = xb[idx * 3 + 2] - qz;
        const size_t o = (((size_t)b * OUTCH + 0) * SS + s) * NSAMP + k;
        out[o + 0 * (size_t)SS * NSAMP] = gx;
        out[o + 1 * (size_t)SS * NSAMP] = gy;
        out[o + 2 * (size_t)SS * NSAMP] = gz;
    }
}

__global__ __launch_bounds__(512, 4) void fused_kernel(
    const float* __restrict__ xyz,      // (B,N,3)
    const float* __restrict__ new_xyz,  // (B,S,3)
    const float* __restrict__ feats,    // (B,C,N)
    int*  __restrict__ idxq,            // ws: (B*S,32)
    int*  __restrict__ done,            // ws: (B) zeroed counters
    float* __restrict__ out)            // (B,67,S,32)
{
    __shared__ float row[NN];           // 64 KB
    __shared__ int   sidx[8][NSAMP];    // 1 KB
    __shared__ int   need_self;

    const int t    = threadIdx.x;       // 0..511
    const int wave = t >> 6;
    const int lane = t & 63;
    const int c    = blockIdx.x & (GPB - 1);   // channel == query group
    const int b    = blockIdx.x >> 6;

    // ---- issue feats row loads early; held in VGPRs across the query phase
    const float* fr = feats + ((size_t)b * CC + c) * NN;
    float4 stg[8];
    #pragma unroll
    for (int i = 0; i < 8; ++i)
        stg[i] = *(const float4*)(fr + (i * 512 + t) * 4);

    // ---- query phase: this block owns queries s in [c*16, c*16+16)
    const float* xb = xyz + (size_t)b * NN * 3;
    const float* nb = new_xyz + (size_t)b * SS * 3;
    #pragma unroll
    for (int r = 0; r < 2; ++r) {
        const int s = c * QPG + wave * 2 + r;
        const float qx = nb[s * 3 + 0];
        const float qy = nb[s * 3 + 1];
        const float qz = nb[s * 3 + 2];
        ball_query_one(xb, qx, qy, qz, b, s, lane, sidx[wave], idxq, out);
    }
    __syncthreads();                    // all 16 idx groups written
    if (t == 0) {
        __threadfence();                // publish idxq before the count bump
        __hip_atomic_fetch_add(done + b, 1, __ATOMIC_RELEASE,
                               __HIP_MEMORY_SCOPE_AGENT);
    }

    // ---- stage feats row to LDS (loads long since landed)
    #pragma unroll
    for (int i = 0; i < 8; ++i)
        *(float4*)(row + (i * 512 + t) * 4) = stg[i];

    // ---- wait for the whole batch's idx (bounded spin + self-compute)
    if (t == 0) {
        int ok = 1, spins = 0;
        while (__hip_atomic_load(done + b, __ATOMIC_ACQUIRE,
                                 __HIP_MEMORY_SCOPE_AGENT) < GPB) {
            __builtin_amdgcn_s_sleep(2);
            if (++spins > (1 << 20)) { ok = 0; break; }   // ~50ms: pathology
        }
        need_self = ok ? 0 : 1;
    }
    __syncthreads();                    // row staged + done-wait complete
    if (need_self) {
        // dispatch pathology: compute ALL of batch b's queries ourselves.
        // idxq/out writes are idempotent (deterministic values) -> safe.
        for (int s = wave; s < SS; s += 8) {
            const float qx = nb[s * 3 + 0];
            const float qy = nb[s * 3 + 1];
            const float qz = nb[s * 3 + 2];
            ball_query_one(xb, qx, qy, qz, b, s, lane, sidx[wave], idxq, out);
        }
        __syncthreads();
    }

    // ---- gather: out[b,3+c,s,k] = row[idx[b,s,k]] (R5-proven body)
    const int k4 = (t & 7) * 4;
    const int s0 = t >> 3;              // 0..63
    const int* ib = idxq + (size_t)b * SS * NSAMP;
    float* ob = out + (((size_t)b * OUTCH + 3 + c) * SS) * NSAMP;
    #pragma unroll
    for (int it = 0; it < 16; ++it) {
        const int s = it * 64 + s0;
        const int4 id = *(const int4*)(ib + (size_t)s * NSAMP + k4);
        float4 v;
        v.x = row[id.x];
        v.y = row[id.y];
        v.z = row[id.z];
        v.w = row[id.w];
        *(float4*)(ob + (size_t)s * NSAMP + k4) = v;
    }
}

// ---------------- fallback: fused per-query kernel (if ws too small) --------
__global__ __launch_bounds__(64) void qg_fused(
    const float* __restrict__ xyz, const float* __restrict__ new_xyz,
    const float* __restrict__ feats, float* __restrict__ out)
{
    const int bs   = blockIdx.x;
    const int b    = bs >> 10;
    const int s    = bs & (SS - 1);
    const int lane = threadIdx.x;

    const float* xb = xyz + (size_t)b * NN * 3;
    const float qx = new_xyz[((size_t)b * SS + s) * 3 + 0];
    const float qy = new_xyz[((size_t)b * SS + s) * 3 + 1];
    const float qz = new_xyz[((size_t)b * SS + s) * 3 + 2];

    __shared__ int sidx[NSAMP];
    int count = 0;
    for (int base = 0; base < NN; base += 64) {
        const int i = base + lane;
        const float dx = qx - xb[i * 3 + 0];
        const float dy = qy - xb[i * 3 + 1];
        const float dz = qz - xb[i * 3 + 2];
        const float d2 = __fadd_rn(__fadd_rn(__fmul_rn(dx, dx),
                                             __fmul_rn(dy, dy)),
                                   __fmul_rn(dz, dz));
        const bool within = d2 < R2;
        const unsigned long long m = __ballot(within);
        if (within) {
            const int pos = count + __popcll(m & ((1ull << lane) - 1ull));
            if (pos < NSAMP) sidx[pos] = i;
        }
        count += __popcll(m);
        if (count >= NSAMP) break;
    }
    __syncthreads();
    const int cnt = count < NSAMP ? count : NSAMP;
    const int first = (cnt > 0) ? sidx[0] : 0;
    if (lane < NSAMP && lane >= cnt) sidx[lane] = first;
    __syncthreads();

    const int k    = lane & 31;
    const int half = lane >> 5;
    const int idx  = sidx[k];
    const size_t obase = (((size_t)b * OUTCH + 0) * SS + s) * NSAMP + k;
    if (half == 0) {
        out[obase + 0 * (size_t)SS * NSAMP] = xb[idx * 3 + 0] - qx;
        out[obase + 1 * (size_t)SS * NSAMP] = xb[idx * 3 + 1] - qy;
        out[obase + 2 * (size_t)SS * NSAMP] = xb[idx * 3 + 2] - qz;
    }
    const float* fb = feats + (size_t)b * CC * NN;
    const size_t fo = (((size_t)b * OUTCH + 3) * SS + s) * NSAMP + k;
    for (int cch = half; cch < CC; cch += 2) {
        out[fo + (size_t)cch * SS * NSAMP] = fb[(size_t)cch * NN + idx];
    }
}

extern "C" void kernel_launch(void* const* d_in, const int* in_sizes, int n_in,
                              void* d_out, int out_size, void* d_ws, size_t ws_size,
                              hipStream_t stream) {
    const float* xyz     = (const float*)d_in[0];
    const float* new_xyz = (const float*)d_in[1];
    const float* feats   = (const float*)d_in[2];
    float* out           = (float*)d_out;

    const size_t idx_bytes  = (size_t)BB * SS * NSAMP * sizeof(int);   // 1 MB
    const size_t need_bytes = idx_bytes + BB * sizeof(int);

    if (ws_size >= need_bytes) {
        int* idxq = (int*)d_ws;
        int* done = (int*)((char*)d_ws + idx_bytes);
        hipMemsetAsync(done, 0, BB * sizeof(int), stream);
        fused_kernel<<<BB * GPB, 512, 0, stream>>>(xyz, new_xyz, feats,
                                                   idxq, done, out);
    } else {
        qg_fused<<<BB * SS, 64, 0, stream>>>(xyz, new_xyz, feats, out);
    }
}

// Round 4
// 117.586 us; speedup vs baseline: 1.7054x; 1.7054x over previous
//
#include <hip/hip_runtime.h>

// QueryAndGroup: ball query (first 32 idx within radius, index order, padded
// with first hit) + grouped_xyz (xyz[idx]-center) + grouped feature gather.
// Shapes: xyz (8,16384,3) f32, new_xyz (8,1024,3) f32, features (8,64,16384) f32
// Out: (8, 3+64, 1024, 32) f32.
//
// R9: revert to the R5-proven two-kernel structure (114.9us measured).
// R8 post-mortem: whole-batch fusion = straggler-gated, 4% VALU / 15% HBM /
// 43% occ -> 117us alone. Two-kernel budget: ~88us fixed harness fills +
// ~27us kernels (gather ~17us vs 16.2 compulsory-HBM floor, query ~9us).
// Kept from R6/R7 (strictly cheaper, query-side only):
//  - v_mbcnt_lo/hi prefix-count instead of popcll(m & below)  (2 VALU vs ~5)
//  - wave-private sidx: s_waitcnt lgkmcnt(0) instead of __syncthreads
//    (waves decoupled; short-scan waves store early)
// Gather body is byte-identical to R5 (R7's async-lds + vmcnt(0) + NT-store
// rewrite cost ~6us: the vmcnt(0) drained the idx prefetch too).

#define BB 8
#define NN 16384
#define SS 1024
#define CC 64
#define NSAMP 32
#define OUTCH (3 + CC)

// float(0.04) to match numpy's weak-scalar promotion (NOT 0.2f*0.2f).
#define R2 0.04f

// ---------------- kernel A: ball query ----------------
// 4 waves/block, one query per wave, 512-pt chunks (loads batched ahead of
// the ballot phase -> one latency per chunk).
__global__ __launch_bounds__(256) void query_kernel(
    const float* __restrict__ xyz,      // (B,N,3)
    const float* __restrict__ new_xyz,  // (B,S,3)
    int* __restrict__ idxq,             // ws: (B*S,32)
    float* __restrict__ out)            // (B,67,S,32)
{
    __shared__ int sidx[4][NSAMP];

    const int t    = threadIdx.x;
    const int wave = t >> 6;
    const int lane = t & 63;
    const int q    = blockIdx.x * 4 + wave;   // 0..8191
    const int b    = q >> 10;
    const int s    = q & (SS - 1);

    const float* xb = xyz + (size_t)b * NN * 3;
    const float qx = new_xyz[((size_t)b * SS + s) * 3 + 0];
    const float qy = new_xyz[((size_t)b * SS + s) * 3 + 1];
    const float qz = new_xyz[((size_t)b * SS + s) * 3 + 2];

    int count = 0;
    for (int base = 0; base < NN; base += 512) {
        float d2[8];
        #pragma unroll
        for (int j = 0; j < 8; ++j) {
            const int i = base + j * 64 + lane;
            const float dx = qx - xb[i * 3 + 0];
            const float dy = qy - xb[i * 3 + 1];
            const float dz = qz - xb[i * 3 + 2];
            // numpy order, no FMA contraction
            d2[j] = __fadd_rn(__fadd_rn(__fmul_rn(dx, dx),
                                        __fmul_rn(dy, dy)),
                              __fmul_rn(dz, dz));
        }
        #pragma unroll
        for (int j = 0; j < 8; ++j) {
            const bool within = d2[j] < R2;
            const unsigned long long m = __ballot(within);
            if (within) {
                // prefix popcount below lane: v_mbcnt_lo/hi (2 VALU)
                const int pre = (int)__builtin_amdgcn_mbcnt_hi(
                    (unsigned)(m >> 32),
                    __builtin_amdgcn_mbcnt_lo((unsigned)m, 0u));
                const int pos = count + pre;
                if (pos < NSAMP) sidx[wave][pos] = base + j * 64 + lane;
            }
            count += __popcll(m);   // uniform -> s_bcnt1
        }
        if (count >= NSAMP) break;   // wave-uniform
    }
    // sidx[wave][*] is wave-private: DS completion suffices, no block barrier
    // (decouples the 4 waves: short-scan waves store out early).
    asm volatile("s_waitcnt lgkmcnt(0)" ::: "memory");
    const int cnt = count < NSAMP ? count : NSAMP;
    const int first = (cnt > 0) ? sidx[wave][0] : 0;
    if (lane < NSAMP && lane >= cnt) sidx[wave][lane] = first;
    asm volatile("s_waitcnt lgkmcnt(0)" ::: "memory");

    if (lane < NSAMP) {
        const int k = lane;
        const int idx = sidx[wave][k];
        idxq[(size_t)q * NSAMP + k] = idx;
        // grouped_xyz -> out channels 0..2 (128B coalesced per channel)
        const float gx = xb[idx * 3 + 0] - qx;
        const float gy = xb[idx * 3 + 1] - qy;
        const float gz = xb[idx * 3 + 2] - qz;
        const size_t o = (((size_t)b * OUTCH + 0) * SS + s) * NSAMP + k;
        out[o + 0 * (size_t)SS * NSAMP] = gx;
        out[o + 1 * (size_t)SS * NSAMP] = gy;
        out[o + 2 * (size_t)SS * NSAMP] = gz;
    }
}

// ---------------- kernel B: row-in-LDS gather (R5-proven body) ----------------
// one block per (b,c): stage feats[b,c,:] (64KB) in LDS, gather via LDS,
// write out[b,3+c,:,:] (128KB) fully coalesced.
__global__ __launch_bounds__(512) void gather_kernel(
    const float* __restrict__ feats,    // (B,C,N)
    const int*   __restrict__ idxq,     // (B*S,32)
    float* __restrict__ out)            // (B,67,S,32)
{
    __shared__ float row[NN];           // 64 KB -> 2 blocks/CU

    const int c = blockIdx.x;           // 0..63
    const int b = blockIdx.y;           // 0..7
    const int t = threadIdx.x;          // 0..511

    // stage the full channel row, coalesced float4 (8 KB per wave-instr)
    const float* fr = feats + ((size_t)b * CC + c) * NN;
    #pragma unroll
    for (int i = 0; i < 8; ++i) {
        const int o = (i * 512 + t) * 4;
        *(float4*)(row + o) = *(const float4*)(fr + o);
    }
    __syncthreads();

    // gather: per iter, 512 threads cover 64 s x 32 k (8 lanes x 4k each)
    const int k4 = (t & 7) * 4;
    const int s0 = t >> 3;              // 0..63
    const int*  ib = idxq + (size_t)b * SS * NSAMP;
    float* ob = out + (((size_t)b * OUTCH + 3 + c) * SS) * NSAMP;
    #pragma unroll
    for (int it = 0; it < 16; ++it) {
        const int s = it * 64 + s0;
        const int4 id = *(const int4*)(ib + (size_t)s * NSAMP + k4);
        float4 v;
        v.x = row[id.x];
        v.y = row[id.y];
        v.z = row[id.z];
        v.w = row[id.w];
        *(float4*)(ob + (size_t)s * NSAMP + k4) = v;
    }
}

// ---------------- fallback: R1 fused kernel (if ws too small) ----------------
__global__ __launch_bounds__(64) void qg_fused(
    const float* __restrict__ xyz, const float* __restrict__ new_xyz,
    const float* __restrict__ feats, float* __restrict__ out)
{
    const int bs   = blockIdx.x;
    const int b    = bs >> 10;
    const int s    = bs & (SS - 1);
    const int lane = threadIdx.x;

    const float* xb = xyz + (size_t)b * NN * 3;
    const float qx = new_xyz[((size_t)b * SS + s) * 3 + 0];
    const float qy = new_xyz[((size_t)b * SS + s) * 3 + 1];
    const float qz = new_xyz[((size_t)b * SS + s) * 3 + 2];

    __shared__ int sidx[NSAMP];
    int count = 0;
    for (int base = 0; base < NN; base += 64) {
        const int i = base + lane;
        const float dx = qx - xb[i * 3 + 0];
        const float dy = qy - xb[i * 3 + 1];
        const float dz = qz - xb[i * 3 + 2];
        const float d2 = __fadd_rn(__fadd_rn(__fmul_rn(dx, dx),
                                             __fmul_rn(dy, dy)),
                                   __fmul_rn(dz, dz));
        const bool within = d2 < R2;
        const unsigned long long m = __ballot(within);
        if (within) {
            const int pos = count + __popcll(m & ((1ull << lane) - 1ull));
            if (pos < NSAMP) sidx[pos] = i;
        }
        count += __popcll(m);
        if (count >= NSAMP) break;
    }
    __syncthreads();
    const int cnt = count < NSAMP ? count : NSAMP;
    const int first = (cnt > 0) ? sidx[0] : 0;
    if (lane < NSAMP && lane >= cnt) sidx[lane] = first;
    __syncthreads();

    const int k    = lane & 31;
    const int half = lane >> 5;
    const int idx  = sidx[k];
    const size_t obase = (((size_t)b * OUTCH + 0) * SS + s) * NSAMP + k;
    if (half == 0) {
        out[obase + 0 * (size_t)SS * NSAMP] = xb[idx * 3 + 0] - qx;
        out[obase + 1 * (size_t)SS * NSAMP] = xb[idx * 3 + 1] - qy;
        out[obase + 2 * (size_t)SS * NSAMP] = xb[idx * 3 + 2] - qz;
    }
    const float* fb = feats + (size_t)b * CC * NN;
    const size_t fo = (((size_t)b * OUTCH + 3) * SS + s) * NSAMP + k;
    for (int cch = half; cch < CC; cch += 2) {
        out[fo + (size_t)cch * SS * NSAMP] = fb[(size_t)cch * NN + idx];
    }
}

extern "C" void kernel_launch(void* const* d_in, const int* in_sizes, int n_in,
                              void* d_out, int out_size, void* d_ws, size_t ws_size,
                              hipStream_t stream) {
    const float* xyz     = (const float*)d_in[0];
    const float* new_xyz = (const float*)d_in[1];
    const float* feats   = (const float*)d_in[2];
    float* out           = (float*)d_out;

    const size_t idx_bytes = (size_t)BB * SS * NSAMP * sizeof(int);     // 1 MB

    if (ws_size >= idx_bytes) {
        int* idxq = (int*)d_ws;
        query_kernel<<<2048, 256, 0, stream>>>(xyz, new_xyz, idxq, out);
        gather_kernel<<<dim3(CC, BB), 512, 0, stream>>>(feats, idxq, out);
    } else {
        qg_fused<<<BB * SS, 64, 0, stream>>>(xyz, new_xyz, feats, out);
    }
}